// Round 1
// baseline (289.010 us; speedup 1.0000x reference)
//
#include <hip/hip_runtime.h>
#include <cmath>

#define C_DIM 2048
#define B_DIM 16
#define H_DIM 16
#define HS_DIM 128
#define T_DIM 4096
#define ATT_SCALE 0.08838834764831845f  // 1/sqrt(128)

// ---------------------------------------------------------------------------
// Kernel 1 & 3: O[16, 2048] = X[16, 2048] @ W[2048, 2048]^T
// One wave per output column n; the wave computes that column for all 16 rows
// so each W row is fetched from HBM exactly once. x re-reads are L2 hits.
// ---------------------------------------------------------------------------
__global__ __launch_bounds__(256) void gemv16_kernel(
    const float* __restrict__ X, const float* __restrict__ W,
    float* __restrict__ O) {
  const int lane = threadIdx.x & 63;
  const int wave = threadIdx.x >> 6;            // 0..3
  const int n = blockIdx.x * 4 + wave;          // output column
  const float* wrow = W + (size_t)n * C_DIM;

  float acc[B_DIM];
#pragma unroll
  for (int m = 0; m < B_DIM; ++m) acc[m] = 0.f;

#pragma unroll
  for (int i = 0; i < C_DIM / 256; ++i) {       // 8 iterations, float4 per lane
    const int j = i * 256 + lane * 4;
    const float4 w4 = *reinterpret_cast<const float4*>(wrow + j);
#pragma unroll
    for (int m = 0; m < B_DIM; ++m) {
      const float4 x4 = *reinterpret_cast<const float4*>(X + m * C_DIM + j);
      acc[m] += w4.x * x4.x + w4.y * x4.y + w4.z * x4.z + w4.w * x4.w;
    }
  }

  // full-wave sum reduction for each of the 16 accumulators
#pragma unroll
  for (int m = 0; m < B_DIM; ++m) {
#pragma unroll
    for (int mask = 32; mask >= 1; mask >>= 1)
      acc[m] += __shfl_xor(acc[m], mask, 64);
  }
  if (lane == 0) {
#pragma unroll
    for (int m = 0; m < B_DIM; ++m) O[(size_t)m * C_DIM + n] = acc[m];
  }
}

// ---------------------------------------------------------------------------
// Kernel 2: decode attention, one block per (b,h), 16 waves, online softmax.
// Wave w owns t in [w*256, w*256+256); lane d holds dims {2d, 2d+1}.
// ---------------------------------------------------------------------------
__global__ __launch_bounds__(1024) void attn_decode_kernel(
    const float* __restrict__ q, const float* __restrict__ k,
    const float* __restrict__ v, float* __restrict__ y) {
  const int bh = blockIdx.x;                    // b*16 + h
  const int lane = threadIdx.x & 63;
  const int wave = threadIdx.x >> 6;            // 0..15

  const float2* kp = reinterpret_cast<const float2*>(k + (size_t)bh * T_DIM * HS_DIM);
  const float2* vp = reinterpret_cast<const float2*>(v + (size_t)bh * T_DIM * HS_DIM);
  const float2 qv = reinterpret_cast<const float2*>(q + (size_t)bh * HS_DIM)[lane];

  float m = -INFINITY, l = 0.f, y0 = 0.f, y1 = 0.f;
  const int t0 = wave * (T_DIM / 16);

#pragma unroll 4
  for (int ti = 0; ti < T_DIM / 16; ++ti) {
    const int t = t0 + ti;
    const float2 kv = kp[(size_t)t * 64 + lane];
    const float2 vv = vp[(size_t)t * 64 + lane];
    float p = kv.x * qv.x + kv.y * qv.y;
#pragma unroll
    for (int mask = 32; mask >= 1; mask >>= 1) p += __shfl_xor(p, mask, 64);
    const float s = p * ATT_SCALE;
    const float mn = fmaxf(m, s);
    const float c = __expf(m - mn);             // exp(-inf)=0 on first iter
    const float e = __expf(s - mn);
    l = l * c + e;
    y0 = fmaf(y0, c, e * vv.x);
    y1 = fmaf(y1, c, e * vv.y);
    m = mn;
  }

  __shared__ float lm[16];
  __shared__ float ll[16];
  __shared__ float ly[16 * HS_DIM];
  ly[wave * HS_DIM + 2 * lane] = y0;
  ly[wave * HS_DIM + 2 * lane + 1] = y1;
  if (lane == 0) { lm[wave] = m; ll[wave] = l; }
  __syncthreads();

  if (wave == 0) {
    float gm = -INFINITY;
#pragma unroll
    for (int w = 0; w < 16; ++w) gm = fmaxf(gm, lm[w]);
    float L = 0.f, a0 = 0.f, a1 = 0.f;
#pragma unroll
    for (int w = 0; w < 16; ++w) {
      const float sc = __expf(lm[w] - gm);
      L += ll[w] * sc;
      a0 = fmaf(ly[w * HS_DIM + lane], sc, a0);
      a1 = fmaf(ly[w * HS_DIM + 64 + lane], sc, a1);
    }
    y[(size_t)bh * HS_DIM + lane] = a0 / L;
    y[(size_t)bh * HS_DIM + 64 + lane] = a1 / L;
  }
}

extern "C" void kernel_launch(void* const* d_in, const int* in_sizes, int n_in,
                              void* d_out, int out_size, void* d_ws, size_t ws_size,
                              hipStream_t stream) {
  const float* x  = (const float*)d_in[0];   // [16, 1, 2048]
  const float* k  = (const float*)d_in[1];   // [16, 16, 4096, 128]
  const float* v  = (const float*)d_in[2];   // [16, 16, 4096, 128]
  const float* Wq = (const float*)d_in[3];   // [2048, 2048]
  const float* Wp = (const float*)d_in[4];   // [2048, 2048]
  float* out = (float*)d_out;                // [16, 1, 2048]

  float* ws   = (float*)d_ws;
  float* q_ws = ws;                          // [16, 2048]
  float* y_ws = ws + B_DIM * C_DIM;          // [16, 2048] (= [B, H, HS] flattened)

  hipLaunchKernelGGL(gemv16_kernel, dim3(C_DIM / 4), dim3(256), 0, stream,
                     x, Wq, q_ws);
  hipLaunchKernelGGL(attn_decode_kernel, dim3(B_DIM * H_DIM), dim3(1024), 0, stream,
                     q_ws, k, v, y_ws);
  hipLaunchKernelGGL(gemv16_kernel, dim3(C_DIM / 4), dim3(256), 0, stream,
                     y_ws, Wp, out);
}

// Round 4
// 277.992 us; speedup vs baseline: 1.0396x; 1.0396x over previous
//
#include <hip/hip_runtime.h>
#include <cmath>

#define C_DIM 2048
#define B_DIM 16
#define H_DIM 16
#define HS_DIM 128
#define T_DIM 4096
#define ATT_SCALE 0.08838834764831845f  // 1/sqrt(128)

// ---------------------------------------------------------------------------
// Kernel 1 & 3: O[16, 2048] = X[16, 2048] @ W[2048, 2048]^T
// One wave per output column n; the wave computes that column for all 16 rows
// so each W row is fetched from HBM exactly once. x re-reads are L2 hits.
// ---------------------------------------------------------------------------
__global__ __launch_bounds__(256) void gemv16_kernel(
    const float* __restrict__ X, const float* __restrict__ W,
    float* __restrict__ O) {
  const int lane = threadIdx.x & 63;
  const int wave = threadIdx.x >> 6;            // 0..3
  const int n = blockIdx.x * 4 + wave;          // output column
  const float* wrow = W + (size_t)n * C_DIM;

  float acc[B_DIM];
#pragma unroll
  for (int m = 0; m < B_DIM; ++m) acc[m] = 0.f;

#pragma unroll
  for (int i = 0; i < C_DIM / 256; ++i) {       // 8 iterations, float4 per lane
    const int j = i * 256 + lane * 4;
    const float4 w4 = *reinterpret_cast<const float4*>(wrow + j);
#pragma unroll
    for (int m = 0; m < B_DIM; ++m) {
      const float4 x4 = *reinterpret_cast<const float4*>(X + m * C_DIM + j);
      acc[m] += w4.x * x4.x + w4.y * x4.y + w4.z * x4.z + w4.w * x4.w;
    }
  }

#pragma unroll
  for (int m = 0; m < B_DIM; ++m) {
#pragma unroll
    for (int mask = 32; mask >= 1; mask >>= 1)
      acc[m] += __shfl_xor(acc[m], mask, 64);
  }
  if (lane == 0) {
#pragma unroll
    for (int m = 0; m < B_DIM; ++m) O[(size_t)m * C_DIM + n] = acc[m];
  }
}

// ---------------------------------------------------------------------------
// Kernel 2: decode attention, one block per (b,h), 16 waves.
// Each lane loads float4 (16B); a 32-lane half-wave covers one full 128-dim
// row, so a wave processes 2 rows/iter. Each half-wave keeps its own online
// softmax state; 32 partials merge via LDS at the end.
// ---------------------------------------------------------------------------
__global__ __launch_bounds__(1024) void attn_decode_kernel(
    const float* __restrict__ q, const float* __restrict__ k,
    const float* __restrict__ v, float* __restrict__ y) {
  const int bh = blockIdx.x;                    // b*16 + h
  const int lane = threadIdx.x & 63;
  const int wave = threadIdx.x >> 6;            // 0..15
  const int half = lane >> 5;                   // which row of the pair
  const int dl = lane & 31;                     // dim-quad index (4 dims each)

  const float4* kp = reinterpret_cast<const float4*>(k + (size_t)bh * T_DIM * HS_DIM);
  const float4* vp = reinterpret_cast<const float4*>(v + (size_t)bh * T_DIM * HS_DIM);
  const float4 qv = reinterpret_cast<const float4*>(q + (size_t)bh * HS_DIM)[dl];

  float m = -INFINITY, l = 0.f;
  float y0 = 0.f, y1 = 0.f, y2 = 0.f, y3 = 0.f;
  const int t0 = wave * (T_DIM / 16);           // 256 rows per wave

#pragma unroll 8
  for (int ti = 0; ti < T_DIM / 32; ++ti) {     // 128 iters, 2 rows each
    const int t = t0 + 2 * ti + half;
    const float4 kv = kp[(size_t)t * 32 + dl];
    const float4 vv = vp[(size_t)t * 32 + dl];
    float p = kv.x * qv.x + kv.y * qv.y + kv.z * qv.z + kv.w * qv.w;
#pragma unroll
    for (int mask = 16; mask >= 1; mask >>= 1) p += __shfl_xor(p, mask, 64);
    const float s = p * ATT_SCALE;
    const float mn = fmaxf(m, s);
    const float c = __expf(m - mn);             // exp(-inf)=0 on first iter
    const float e = __expf(s - mn);
    l = l * c + e;
    y0 = fmaf(y0, c, e * vv.x);
    y1 = fmaf(y1, c, e * vv.y);
    y2 = fmaf(y2, c, e * vv.z);
    y3 = fmaf(y3, c, e * vv.w);
    m = mn;
  }

  // 32 partials: index p32 = wave*2 + half, each holds m, l, y[128]
  __shared__ float lm[32];
  __shared__ float ll[32];
  __shared__ float ly[32 * HS_DIM];
  float4* ly4 = reinterpret_cast<float4*>(ly);
  const int p32 = wave * 2 + half;
  ly4[p32 * 32 + dl] = make_float4(y0, y1, y2, y3);
  if (dl == 0) { lm[p32] = m; ll[p32] = l; }
  __syncthreads();

  if (wave == 0) {
    float gm = -INFINITY;
#pragma unroll
    for (int w = 0; w < 32; ++w) gm = fmaxf(gm, lm[w]);
    float L = 0.f, a0 = 0.f, a1 = 0.f;
#pragma unroll
    for (int w = 0; w < 32; ++w) {
      const float sc = __expf(lm[w] - gm);
      L += ll[w] * sc;
      a0 = fmaf(ly[w * HS_DIM + lane], sc, a0);
      a1 = fmaf(ly[w * HS_DIM + 64 + lane], sc, a1);
    }
    y[(size_t)bh * HS_DIM + lane] = a0 / L;
    y[(size_t)bh * HS_DIM + 64 + lane] = a1 / L;
  }
}

extern "C" void kernel_launch(void* const* d_in, const int* in_sizes, int n_in,
                              void* d_out, int out_size, void* d_ws, size_t ws_size,
                              hipStream_t stream) {
  const float* x  = (const float*)d_in[0];   // [16, 1, 2048]
  const float* k  = (const float*)d_in[1];   // [16, 16, 4096, 128]
  const float* v  = (const float*)d_in[2];   // [16, 16, 4096, 128]
  const float* Wq = (const float*)d_in[3];   // [2048, 2048]
  const float* Wp = (const float*)d_in[4];   // [2048, 2048]
  float* out = (float*)d_out;                // [16, 1, 2048]

  float* ws   = (float*)d_ws;
  float* q_ws = ws;                          // [16, 2048]
  float* y_ws = ws + B_DIM * C_DIM;          // [16, 2048] (= [B, H, HS] flattened)

  hipLaunchKernelGGL(gemv16_kernel, dim3(C_DIM / 4), dim3(256), 0, stream,
                     x, Wq, q_ws);
  hipLaunchKernelGGL(attn_decode_kernel, dim3(B_DIM * H_DIM), dim3(1024), 0, stream,
                     q_ws, k, v, y_ws);
  hipLaunchKernelGGL(gemv16_kernel, dim3(C_DIM / 4), dim3(256), 0, stream,
                     y_ws, Wp, out);
}